// Round 18
// baseline (202.394 us; speedup 1.0000x reference)
//
#include <hip/hip_runtime.h>

#define BATCH 16
#define PS 49                // nodes per partition
#define NPART 1024           // 1024*49 = 50176 >= 50001
#define SB 256               // hist/scatter blocks
#define TPB 1024
#define LDSCAP 3840          // records staged in LDS (mean 3125, +12.8 sigma); 61440 B

#define TWO_LOG2E 2.8853900817779268f   // 2*log2(e)

typedef unsigned int uint4v __attribute__((ext_vector_type(4)));

// Histogram of OWNER-endpoint partitions + fused aux build (LDS tile-transpose).
__global__ __launch_bounds__(TPB)
void hist1(const int* __restrict__ src, const int* __restrict__ des,
           const float* __restrict__ x, float* __restrict__ auxT,
           unsigned* __restrict__ blockHist, int E, int n) {
    __shared__ unsigned h[NPART];
    __shared__ float tile[64 * 17];
    int tid = threadIdx.x;
    for (int i = tid; i < NPART; i += TPB) h[i] = 0;
    if (blockIdx.x == 0 && tid < BATCH) auxT[tid] = 0.0f;   // node-0 zero row
    // aux build: 64-node x 16-batch tiles, coalesced read AND write
    int nTiles = (n + 63) / 64;
    for (int t0 = blockIdx.x; t0 < nTiles; t0 += gridDim.x) {
        int i0 = t0 * 64;
        int b = tid >> 6, ii = tid & 63;
        float v = (i0 + ii < n) ? x[(size_t)b * n + i0 + ii] : 0.0f;
        __syncthreads();
        tile[ii * 17 + b] = v;
        __syncthreads();
        int i2 = i0 + (tid >> 4);
        if (i2 < n)
            auxT[(size_t)(i2 + 1) * BATCH + (tid & 15)] = tile[(tid >> 4) * 17 + (tid & 15)];
    }
    __syncthreads();
    long t = (long)blockIdx.x * TPB + tid;
    long stride = (long)gridDim.x * TPB * 4;
    for (long e0 = t * 4; e0 < E; e0 += stride) {
        int ne = (int)min((long)4, (long)E - e0);
        int ss[4], dd[4];
        if (ne == 4) {
            int4 sv = *(const int4*)(src + e0);
            int4 dv = *(const int4*)(des + e0);
            ss[0]=sv.x; ss[1]=sv.y; ss[2]=sv.z; ss[3]=sv.w;
            dd[0]=dv.x; dd[1]=dv.y; dd[2]=dv.z; dd[3]=dv.w;
        } else {
            for (int j = 0; j < ne; ++j) { ss[j] = src[e0+j]; dd[j] = des[e0+j]; }
        }
        for (int j = 0; j < ne; ++j) {
            atomicAdd(&h[ss[j] / PS], 1u);
            atomicAdd(&h[dd[j] / PS], 1u);
        }
    }
    __syncthreads();
    for (int i = tid; i < NPART; i += TPB)
        blockHist[(size_t)blockIdx.x * NPART + i] = h[i];
}

// Grid-parallel per-bin totals: 64 bins/block x 16 threads. Grid = NPART/64 = 16.
__global__ __launch_bounds__(TPB)
void totals_k(const unsigned* __restrict__ blockHist, unsigned* __restrict__ binTotal) {
    int tid = threadIdx.x;
    int bin = blockIdx.x * 64 + (tid >> 4);
    int j = tid & 15;
    unsigned s = 0;
    for (int r = j; r < SB; r += 16) s += blockHist[(size_t)r * NPART + bin];
#pragma unroll
    for (int m = 1; m < 16; m <<= 1) s += __shfl_xor(s, m, 64);
    if (j == 0) binTotal[bin] = s;
}

// One block: exclusive scan of 1024 bin totals -> partStart[0..1024].
__global__ __launch_bounds__(TPB)
void scan_bins(const unsigned* __restrict__ binTotal, unsigned* __restrict__ partStart) {
    __shared__ unsigned wsum[16];
    int tid = threadIdx.x;
    int lane = tid & 63, wv = tid >> 6;
    unsigned v = binTotal[tid];
    unsigned inc = v;
    for (int off = 1; off < 64; off <<= 1) {
        unsigned t = __shfl_up(inc, off, 64);
        if (lane >= off) inc += t;
    }
    if (lane == 63) wsum[wv] = inc;
    __syncthreads();
    if (tid < 16) {
        unsigned w = wsum[tid], winc = w;
        for (int off = 1; off < 16; off <<= 1) {
            unsigned t = __shfl_up(winc, off, 64);
            if (tid >= off) winc += t;
        }
        wsum[tid] = winc - w;
    }
    __syncthreads();
    unsigned excl = (inc - v) + wsum[wv];
    partStart[tid] = excl;
    if (tid == TPB - 1) partStart[NPART] = excl + v;
}

// Grid-parallel: blockHist -> per-(block,bin) scatter offsets. 64 bins/block x 16.
__global__ __launch_bounds__(TPB)
void offs_k(unsigned* __restrict__ blockHist, const unsigned* __restrict__ partStart) {
    int tid = threadIdx.x;
    int binLocal = tid >> 4;
    int bin = blockIdx.x * 64 + binLocal;
    int j = tid & 15;
    const int per = SB / 16;   // 16
    unsigned ls = 0;
    for (int r = j * per; r < (j + 1) * per; ++r)
        ls += blockHist[(size_t)r * NPART + bin];
    int waveBase = (binLocal & 3) * 16;
    unsigned excl = 0;
    for (int k = 0; k < 16; ++k) {
        unsigned v = __shfl(ls, waveBase + k, 64);
        if (k < j) excl += v;
    }
    unsigned run = partStart[bin] + excl;
    for (int r = j * per; r < (j + 1) * per; ++r) {
        unsigned tmp = blockHist[(size_t)r * NPART + bin];
        blockHist[(size_t)r * NPART + bin] = run;
        run += tmp;
    }
}

// Emit 2 owner-endpoint records per edge via NONTEMPORAL stores (no RFO/L2 alloc).
//   owner=s: {s|d<<16, -a,  w*K, c*K};  owner=d: {d|s<<16, +a, -w*K, c*K}
__global__ __launch_bounds__(TPB)
void scatter1(const int* __restrict__ src, const int* __restrict__ des,
              const float* __restrict__ param, const unsigned* __restrict__ offsets,
              uint4* __restrict__ bins, int E) {
    __shared__ unsigned offs[NPART];
    int tid = threadIdx.x;
    for (int i = tid; i < NPART; i += TPB)
        offs[i] = offsets[(size_t)blockIdx.x * NPART + i];
    __syncthreads();
    uint4v* binv = (uint4v*)bins;
    long t = (long)blockIdx.x * TPB + tid;
    long stride = (long)gridDim.x * TPB * 4;
    for (long e0 = t * 4; e0 < E; e0 += stride) {
        int ne = (int)min((long)4, (long)E - e0);
        int ss[4], dd[4];
        float aa[4], ww[4], cc[4];
        if (ne == 4) {
            int4 sv = *(const int4*)(src + e0);
            int4 dv = *(const int4*)(des + e0);
            float4 av = *(const float4*)(param + e0);
            float4 wv = *(const float4*)(param + E + e0);
            float4 cv = *(const float4*)(param + 2 * (size_t)E + e0);
            ss[0]=sv.x; ss[1]=sv.y; ss[2]=sv.z; ss[3]=sv.w;
            dd[0]=dv.x; dd[1]=dv.y; dd[2]=dv.z; dd[3]=dv.w;
            aa[0]=av.x; aa[1]=av.y; aa[2]=av.z; aa[3]=av.w;
            ww[0]=wv.x; ww[1]=wv.y; ww[2]=wv.z; ww[3]=wv.w;
            cc[0]=cv.x; cc[1]=cv.y; cc[2]=cv.z; cc[3]=cv.w;
        } else {
            for (int j = 0; j < ne; ++j) {
                ss[j] = src[e0+j]; dd[j] = des[e0+j];
                aa[j] = param[e0+j]; ww[j] = param[E + e0 + j];
                cc[j] = param[2 * (size_t)E + e0 + j];
            }
        }
        for (int j = 0; j < ne; ++j) {
            int s = ss[j], d = dd[j];
            float wq = ww[j] * TWO_LOG2E, cq = cc[j] * TWO_LOG2E;
            unsigned slot = atomicAdd(&offs[s / PS], 1u);
            uint4v r1 = {(unsigned)s | ((unsigned)d << 16), __float_as_uint(-aa[j]),
                         __float_as_uint(wq), __float_as_uint(cq)};
            __builtin_nontemporal_store(r1, &binv[slot]);
            unsigned slot2 = atomicAdd(&offs[d / PS], 1u);
            uint4v r2 = {(unsigned)d | ((unsigned)s << 16), __float_as_uint(aa[j]),
                         __float_as_uint(-wq), __float_as_uint(cq)};
            __builtin_nontemporal_store(r2, &binv[slot2]);
        }
    }
}

// st for one record given delta; a2 = 2*a hoisted.
static __device__ __forceinline__ float edge_eval(float a, float a2, float wq, float cq,
                                                  float dv) {
    float ez = __builtin_amdgcn_exp2f(__builtin_fmaf(wq, dv, cq));
    float r = __builtin_amdgcn_rcpf(ez + 1.0f);
    return __builtin_fmaf(-a2, r, a);   // a*(1-2r)
}

// Fused: counting-sort bin into LDS (wave-parallel prefix), then one wave per
// node accumulates (registers + shfl) and writes out[b][node-1] directly.
__global__ __launch_bounds__(TPB)
void sort_accumulate(const uint4* __restrict__ bins, const unsigned* __restrict__ partStart,
                     const float* __restrict__ auxT, float* __restrict__ out, int n) {
    extern __shared__ uint4 srec[];                 // [LDSCAP]
    unsigned* bump = (unsigned*)(srec + LDSCAP);    // [PS]
    unsigned* ns   = bump + PS;                     // [PS+1]
    int p = blockIdx.x;
    int tid = threadIdx.x;
    int lane = tid & 63;
    int wv = tid >> 6;
    unsigned lo = partStart[p], hi = partStart[p + 1];
    unsigned cl = min(hi - lo, (unsigned)LDSCAP);
    int base = p * PS;

    for (int i = tid; i < PS; i += TPB) bump[i] = 0;
    __syncthreads();
    // pass 1: histogram by owner node (keys only)
    const unsigned* keys = (const unsigned*)bins;
    for (unsigned k = tid; k < cl; k += TPB) {
        unsigned o = keys[(size_t)(lo + k) * 4] & 0xFFFFu;
        atomicAdd(&bump[o - (unsigned)base], 1u);
    }
    __syncthreads();
    // wave-parallel exclusive prefix over PS=49 bins (wave 0)
    if (wv == 0) {
        unsigned v = (lane < PS) ? bump[lane] : 0u;
        unsigned inc = v;
        for (int off = 1; off < 64; off <<= 1) {
            unsigned t = __shfl_up(inc, off, 64);
            if (lane >= off) inc += t;
        }
        unsigned excl = inc - v;
        if (lane < PS) { ns[lane] = excl; bump[lane] = excl; }
        if (lane == PS - 1) ns[PS] = inc;
    }
    __syncthreads();
    // pass 2: scatter global bin -> LDS sorted (bin L2/L3-hot from pass 1)
    for (unsigned k = tid; k < cl; k += TPB) {
        uint4 rec = bins[lo + k];
        unsigned slot = atomicAdd(&bump[(rec.x & 0xFFFFu) - (unsigned)base], 1u);
        srec[slot] = rec;
    }
    __syncthreads();
    // pass 3: wave per node, 16 records in flight, lane-quad owns 4 batches
    int ri = lane >> 2, lj = lane & 3;
    const float4* aux4 = (const float4*)auxT;
    for (int nl = wv; nl < PS; nl += TPB / 64) {
        int node = base + nl;
        if (node == 0 || node > n) continue;
        unsigned l2 = ns[nl], h2 = ns[nl + 1];
        float4 vo = aux4[(size_t)node * 4 + lj];
        float ax = 0.0f, ay = 0.0f, az = 0.0f, as_ = 0.0f;
        for (unsigned kk = l2; kk < h2; kk += 16) {
            unsigned k = kk + (unsigned)ri;
            uint4 rec;
            if (k < h2) rec = srec[k];
            else { rec.x = 0u; rec.y = 0u; rec.z = 0u; rec.w = 0u; }
            unsigned rem = rec.x >> 16;
            float4 vr = aux4[(size_t)rem * 4 + lj];
            float a = __uint_as_float(rec.y);
            float a2 = a + a;
            float wq = __uint_as_float(rec.z);
            float cq = __uint_as_float(rec.w);
            ax  += edge_eval(a, a2, wq, cq, vo.x - vr.x);
            ay  += edge_eval(a, a2, wq, cq, vo.y - vr.y);
            az  += edge_eval(a, a2, wq, cq, vo.z - vr.z);
            as_ += edge_eval(a, a2, wq, cq, vo.w - vr.w);
        }
        // overflow tail (normally empty): filtered scan of un-staged records
        for (unsigned kk = lo + cl; kk < hi; kk += 16) {
            unsigned k = kk + (unsigned)ri;
            uint4 rec;
            if (k < hi) rec = bins[k];
            else { rec.x = 0u; rec.y = 0u; rec.z = 0u; rec.w = 0u; }
            if ((int)(rec.x & 0xFFFFu) != node) rec.y = 0u;   // a=0 -> no contribution
            unsigned rem = rec.x >> 16;
            float4 vr = aux4[(size_t)rem * 4 + lj];
            float a = __uint_as_float(rec.y);
            float a2 = a + a;
            float wq = __uint_as_float(rec.z);
            float cq = __uint_as_float(rec.w);
            ax  += edge_eval(a, a2, wq, cq, vo.x - vr.x);
            ay  += edge_eval(a, a2, wq, cq, vo.y - vr.y);
            az  += edge_eval(a, a2, wq, cq, vo.z - vr.z);
            as_ += edge_eval(a, a2, wq, cq, vo.w - vr.w);
        }
#pragma unroll
        for (int m = 4; m < 64; m <<= 1) {
            ax  += __shfl_xor(ax, m, 64);
            ay  += __shfl_xor(ay, m, 64);
            az  += __shfl_xor(az, m, 64);
            as_ += __shfl_xor(as_, m, 64);
        }
        if (lane < 4) {
            int j = node - 1;
            int b0 = lj * 4;
            out[(size_t)(b0 + 0) * n + j] = ax;
            out[(size_t)(b0 + 1) * n + j] = ay;
            out[(size_t)(b0 + 2) * n + j] = az;
            out[(size_t)(b0 + 3) * n + j] = as_;
        }
    }
}

// ---------------- fallback: direct device atomics ----------------
__global__ void edge_direct(const float* __restrict__ param,
                            const int* __restrict__ src,
                            const int* __restrict__ des,
                            const float* __restrict__ x,
                            float* __restrict__ out, int E, int n) {
    int e = blockIdx.x * blockDim.x + threadIdx.x;
    if (e >= E) return;
    float a = param[e], w = param[E + e], c = param[2 * E + e];
    int s = src[e], d = des[e];
#pragma unroll
    for (int b = 0; b < BATCH; ++b) {
        float vs = s ? x[(size_t)b * n + (s - 1)] : 0.0f;
        float vd = d ? x[(size_t)b * n + (d - 1)] : 0.0f;
        float st = a * tanhf(w * (vs - vd) + c);
        if (s) atomicAdd(out + (size_t)b * n + (s - 1), -st);
        if (d) atomicAdd(out + (size_t)b * n + (d - 1), st);
    }
}

extern "C" void kernel_launch(void* const* d_in, const int* in_sizes, int n_in,
                              void* d_out, int out_size, void* d_ws, size_t ws_size,
                              hipStream_t stream) {
    const float* x     = (const float*)d_in[1];
    const float* param = (const float*)d_in[2];
    const int*   src   = (const int*)d_in[3];
    const int*   des   = (const int*)d_in[4];
    float* out = (float*)d_out;

    int E = in_sizes[3];
    int n = in_sizes[1] / BATCH;   // N = 50000

    auto alignup = [](size_t v) { return (v + 255) & ~(size_t)255; };
    size_t auxBytes  = alignup((size_t)(n + 1) * BATCH * sizeof(float));
    size_t bhBytes   = alignup((size_t)SB * NPART * sizeof(unsigned));
    size_t psBytes   = alignup((size_t)(NPART + 1) * sizeof(unsigned));
    size_t btBytes   = alignup((size_t)NPART * sizeof(unsigned));
    size_t binBytes  = alignup((size_t)2 * E * sizeof(uint4));
    size_t need      = auxBytes + bhBytes + psBytes + btBytes + binBytes;

    size_t saLds = (size_t)LDSCAP * sizeof(uint4) + (2 * PS + 1 + 8) * sizeof(unsigned);

    if (ws_size >= need && (n + 1) <= NPART * PS && n <= 65534) {
        char* w = (char*)d_ws;
        float*    auxT      = (float*)w;     w += auxBytes;
        unsigned* blockHist = (unsigned*)w;  w += bhBytes;
        unsigned* partStart = (unsigned*)w;  w += psBytes;
        unsigned* binTotal  = (unsigned*)w;  w += btBytes;
        uint4*    bins      = (uint4*)w;

        hist1<<<SB, TPB, 0, stream>>>(src, des, x, auxT, blockHist, E, n);
        totals_k<<<NPART / 64, TPB, 0, stream>>>(blockHist, binTotal);
        scan_bins<<<1, TPB, 0, stream>>>(binTotal, partStart);
        offs_k<<<NPART / 64, TPB, 0, stream>>>(blockHist, partStart);
        scatter1<<<SB, TPB, 0, stream>>>(src, des, param, blockHist, bins, E);
        sort_accumulate<<<NPART, TPB, saLds, stream>>>(bins, partStart, auxT, out, n);
        return;
    }

    (void)hipMemsetAsync(out, 0, (size_t)out_size * sizeof(float), stream);
    edge_direct<<<(E + 255) / 256, 256, 0, stream>>>(param, src, des, x, out, E, n);
}

// Round 19
// 114.006 us; speedup vs baseline: 1.7753x; 1.7753x over previous
//
#include <hip/hip_runtime.h>

#define BATCH 16
#define PS 49                // nodes per partition
#define NPART 1024           // 1024*49 = 50176 >= 50001
#define SB 256               // hist/scatter blocks
#define TPB 1024
#define LDSCAP 3840          // records staged in LDS (mean 3125, +12.8 sigma); 61440 B

#define TWO_LOG2E 2.8853900817779268f   // 2*log2(e)

// Histogram of OWNER-endpoint partitions + fused aux build (LDS tile-transpose).
__global__ __launch_bounds__(TPB)
void hist1(const int* __restrict__ src, const int* __restrict__ des,
           const float* __restrict__ x, float* __restrict__ auxT,
           unsigned* __restrict__ blockHist, int E, int n) {
    __shared__ unsigned h[NPART];
    __shared__ float tile[64 * 17];
    int tid = threadIdx.x;
    for (int i = tid; i < NPART; i += TPB) h[i] = 0;
    if (blockIdx.x == 0 && tid < BATCH) auxT[tid] = 0.0f;   // node-0 zero row
    // aux build: 64-node x 16-batch tiles, coalesced read AND write
    int nTiles = (n + 63) / 64;
    for (int t0 = blockIdx.x; t0 < nTiles; t0 += gridDim.x) {
        int i0 = t0 * 64;
        int b = tid >> 6, ii = tid & 63;
        float v = (i0 + ii < n) ? x[(size_t)b * n + i0 + ii] : 0.0f;
        __syncthreads();
        tile[ii * 17 + b] = v;
        __syncthreads();
        int i2 = i0 + (tid >> 4);
        if (i2 < n)
            auxT[(size_t)(i2 + 1) * BATCH + (tid & 15)] = tile[(tid >> 4) * 17 + (tid & 15)];
    }
    __syncthreads();
    long t = (long)blockIdx.x * TPB + tid;
    long stride = (long)gridDim.x * TPB * 4;
    for (long e0 = t * 4; e0 < E; e0 += stride) {
        int ne = (int)min((long)4, (long)E - e0);
        int ss[4], dd[4];
        if (ne == 4) {
            int4 sv = *(const int4*)(src + e0);
            int4 dv = *(const int4*)(des + e0);
            ss[0]=sv.x; ss[1]=sv.y; ss[2]=sv.z; ss[3]=sv.w;
            dd[0]=dv.x; dd[1]=dv.y; dd[2]=dv.z; dd[3]=dv.w;
        } else {
            for (int j = 0; j < ne; ++j) { ss[j] = src[e0+j]; dd[j] = des[e0+j]; }
        }
        for (int j = 0; j < ne; ++j) {
            atomicAdd(&h[ss[j] / PS], 1u);
            atomicAdd(&h[dd[j] / PS], 1u);
        }
    }
    __syncthreads();
    for (int i = tid; i < NPART; i += TPB)
        blockHist[(size_t)blockIdx.x * NPART + i] = h[i];
}

// Grid-parallel per-bin totals: 64 bins/block x 16 threads. Grid = NPART/64 = 16.
__global__ __launch_bounds__(TPB)
void totals_k(const unsigned* __restrict__ blockHist, unsigned* __restrict__ binTotal) {
    int tid = threadIdx.x;
    int bin = blockIdx.x * 64 + (tid >> 4);
    int j = tid & 15;
    unsigned s = 0;
    for (int r = j; r < SB; r += 16) s += blockHist[(size_t)r * NPART + bin];
#pragma unroll
    for (int m = 1; m < 16; m <<= 1) s += __shfl_xor(s, m, 64);
    if (j == 0) binTotal[bin] = s;
}

// One block: exclusive scan of 1024 bin totals -> partStart[0..1024].
__global__ __launch_bounds__(TPB)
void scan_bins(const unsigned* __restrict__ binTotal, unsigned* __restrict__ partStart) {
    __shared__ unsigned wsum[16];
    int tid = threadIdx.x;
    int lane = tid & 63, wv = tid >> 6;
    unsigned v = binTotal[tid];
    unsigned inc = v;
    for (int off = 1; off < 64; off <<= 1) {
        unsigned t = __shfl_up(inc, off, 64);
        if (lane >= off) inc += t;
    }
    if (lane == 63) wsum[wv] = inc;
    __syncthreads();
    if (tid < 16) {
        unsigned w = wsum[tid], winc = w;
        for (int off = 1; off < 16; off <<= 1) {
            unsigned t = __shfl_up(winc, off, 64);
            if (tid >= off) winc += t;
        }
        wsum[tid] = winc - w;
    }
    __syncthreads();
    unsigned excl = (inc - v) + wsum[wv];
    partStart[tid] = excl;
    if (tid == TPB - 1) partStart[NPART] = excl + v;
}

// Grid-parallel: blockHist -> per-(block,bin) scatter offsets. 64 bins/block x 16.
__global__ __launch_bounds__(TPB)
void offs_k(unsigned* __restrict__ blockHist, const unsigned* __restrict__ partStart) {
    int tid = threadIdx.x;
    int binLocal = tid >> 4;
    int bin = blockIdx.x * 64 + binLocal;
    int j = tid & 15;
    const int per = SB / 16;   // 16
    unsigned ls = 0;
    for (int r = j * per; r < (j + 1) * per; ++r)
        ls += blockHist[(size_t)r * NPART + bin];
    int waveBase = (binLocal & 3) * 16;
    unsigned excl = 0;
    for (int k = 0; k < 16; ++k) {
        unsigned v = __shfl(ls, waveBase + k, 64);
        if (k < j) excl += v;
    }
    unsigned run = partStart[bin] + excl;
    for (int r = j * per; r < (j + 1) * per; ++r) {
        unsigned tmp = blockHist[(size_t)r * NPART + bin];
        blockHist[(size_t)r * NPART + bin] = run;
        run += tmp;
    }
}

// Emit 2 owner-endpoint records per edge (plain stores; L2 write-combining helps):
//   owner=s: {s|d<<16, -a,  w*K, c*K};  owner=d: {d|s<<16, +a, -w*K, c*K}
__global__ __launch_bounds__(TPB)
void scatter1(const int* __restrict__ src, const int* __restrict__ des,
              const float* __restrict__ param, const unsigned* __restrict__ offsets,
              uint4* __restrict__ bins, int E) {
    __shared__ unsigned offs[NPART];
    int tid = threadIdx.x;
    for (int i = tid; i < NPART; i += TPB)
        offs[i] = offsets[(size_t)blockIdx.x * NPART + i];
    __syncthreads();
    long t = (long)blockIdx.x * TPB + tid;
    long stride = (long)gridDim.x * TPB * 4;
    for (long e0 = t * 4; e0 < E; e0 += stride) {
        int ne = (int)min((long)4, (long)E - e0);
        int ss[4], dd[4];
        float aa[4], ww[4], cc[4];
        if (ne == 4) {
            int4 sv = *(const int4*)(src + e0);
            int4 dv = *(const int4*)(des + e0);
            float4 av = *(const float4*)(param + e0);
            float4 wv = *(const float4*)(param + E + e0);
            float4 cv = *(const float4*)(param + 2 * (size_t)E + e0);
            ss[0]=sv.x; ss[1]=sv.y; ss[2]=sv.z; ss[3]=sv.w;
            dd[0]=dv.x; dd[1]=dv.y; dd[2]=dv.z; dd[3]=dv.w;
            aa[0]=av.x; aa[1]=av.y; aa[2]=av.z; aa[3]=av.w;
            ww[0]=wv.x; ww[1]=wv.y; ww[2]=wv.z; ww[3]=wv.w;
            cc[0]=cv.x; cc[1]=cv.y; cc[2]=cv.z; cc[3]=cv.w;
        } else {
            for (int j = 0; j < ne; ++j) {
                ss[j] = src[e0+j]; dd[j] = des[e0+j];
                aa[j] = param[e0+j]; ww[j] = param[E + e0 + j];
                cc[j] = param[2 * (size_t)E + e0 + j];
            }
        }
        for (int j = 0; j < ne; ++j) {
            int s = ss[j], d = dd[j];
            float wq = ww[j] * TWO_LOG2E, cq = cc[j] * TWO_LOG2E;
            unsigned slot = atomicAdd(&offs[s / PS], 1u);
            bins[slot] = make_uint4((unsigned)s | ((unsigned)d << 16),
                                    __float_as_uint(-aa[j]), __float_as_uint(wq),
                                    __float_as_uint(cq));
            unsigned slot2 = atomicAdd(&offs[d / PS], 1u);
            bins[slot2] = make_uint4((unsigned)d | ((unsigned)s << 16),
                                     __float_as_uint(aa[j]), __float_as_uint(-wq),
                                     __float_as_uint(cq));
        }
    }
}

// st for one record given delta; a2 = 2*a hoisted.
static __device__ __forceinline__ float edge_eval(float a, float a2, float wq, float cq,
                                                  float dv) {
    float ez = __builtin_amdgcn_exp2f(__builtin_fmaf(wq, dv, cq));
    float r = __builtin_amdgcn_rcpf(ez + 1.0f);
    return __builtin_fmaf(-a2, r, a);   // a*(1-2r)
}

// Fused: counting-sort bin into LDS (wave-parallel prefix), then one wave per
// node accumulates (registers + shfl) and writes out[b][node-1] directly.
__global__ __launch_bounds__(TPB)
void sort_accumulate(const uint4* __restrict__ bins, const unsigned* __restrict__ partStart,
                     const float* __restrict__ auxT, float* __restrict__ out, int n) {
    extern __shared__ uint4 srec[];                 // [LDSCAP]
    unsigned* bump = (unsigned*)(srec + LDSCAP);    // [PS]
    unsigned* ns   = bump + PS;                     // [PS+1]
    int p = blockIdx.x;
    int tid = threadIdx.x;
    int lane = tid & 63;
    int wv = tid >> 6;
    unsigned lo = partStart[p], hi = partStart[p + 1];
    unsigned cl = min(hi - lo, (unsigned)LDSCAP);
    int base = p * PS;

    for (int i = tid; i < PS; i += TPB) bump[i] = 0;
    __syncthreads();
    // pass 1: histogram by owner node (keys only)
    const unsigned* keys = (const unsigned*)bins;
    for (unsigned k = tid; k < cl; k += TPB) {
        unsigned o = keys[(size_t)(lo + k) * 4] & 0xFFFFu;
        atomicAdd(&bump[o - (unsigned)base], 1u);
    }
    __syncthreads();
    // wave-parallel exclusive prefix over PS=49 bins (wave 0)
    if (wv == 0) {
        unsigned v = (lane < PS) ? bump[lane] : 0u;
        unsigned inc = v;
        for (int off = 1; off < 64; off <<= 1) {
            unsigned t = __shfl_up(inc, off, 64);
            if (lane >= off) inc += t;
        }
        unsigned excl = inc - v;
        if (lane < PS) { ns[lane] = excl; bump[lane] = excl; }
        if (lane == PS - 1) ns[PS] = inc;
    }
    __syncthreads();
    // pass 2: scatter global bin -> LDS sorted (bin L2/L3-hot from pass 1)
    for (unsigned k = tid; k < cl; k += TPB) {
        uint4 rec = bins[lo + k];
        unsigned slot = atomicAdd(&bump[(rec.x & 0xFFFFu) - (unsigned)base], 1u);
        srec[slot] = rec;
    }
    __syncthreads();
    // pass 3: wave per node, 16 records in flight, lane-quad owns 4 batches
    int ri = lane >> 2, lj = lane & 3;
    const float4* aux4 = (const float4*)auxT;
    for (int nl = wv; nl < PS; nl += TPB / 64) {
        int node = base + nl;
        if (node == 0 || node > n) continue;
        unsigned l2 = ns[nl], h2 = ns[nl + 1];
        float4 vo = aux4[(size_t)node * 4 + lj];
        float ax = 0.0f, ay = 0.0f, az = 0.0f, as_ = 0.0f;
        for (unsigned kk = l2; kk < h2; kk += 16) {
            unsigned k = kk + (unsigned)ri;
            uint4 rec;
            if (k < h2) rec = srec[k];
            else { rec.x = 0u; rec.y = 0u; rec.z = 0u; rec.w = 0u; }
            unsigned rem = rec.x >> 16;
            float4 vr = aux4[(size_t)rem * 4 + lj];
            float a = __uint_as_float(rec.y);
            float a2 = a + a;
            float wq = __uint_as_float(rec.z);
            float cq = __uint_as_float(rec.w);
            ax  += edge_eval(a, a2, wq, cq, vo.x - vr.x);
            ay  += edge_eval(a, a2, wq, cq, vo.y - vr.y);
            az  += edge_eval(a, a2, wq, cq, vo.z - vr.z);
            as_ += edge_eval(a, a2, wq, cq, vo.w - vr.w);
        }
        // overflow tail (normally empty): filtered scan of un-staged records
        for (unsigned kk = lo + cl; kk < hi; kk += 16) {
            unsigned k = kk + (unsigned)ri;
            uint4 rec;
            if (k < hi) rec = bins[k];
            else { rec.x = 0u; rec.y = 0u; rec.z = 0u; rec.w = 0u; }
            if ((int)(rec.x & 0xFFFFu) != node) rec.y = 0u;   // a=0 -> no contribution
            unsigned rem = rec.x >> 16;
            float4 vr = aux4[(size_t)rem * 4 + lj];
            float a = __uint_as_float(rec.y);
            float a2 = a + a;
            float wq = __uint_as_float(rec.z);
            float cq = __uint_as_float(rec.w);
            ax  += edge_eval(a, a2, wq, cq, vo.x - vr.x);
            ay  += edge_eval(a, a2, wq, cq, vo.y - vr.y);
            az  += edge_eval(a, a2, wq, cq, vo.z - vr.z);
            as_ += edge_eval(a, a2, wq, cq, vo.w - vr.w);
        }
#pragma unroll
        for (int m = 4; m < 64; m <<= 1) {
            ax  += __shfl_xor(ax, m, 64);
            ay  += __shfl_xor(ay, m, 64);
            az  += __shfl_xor(az, m, 64);
            as_ += __shfl_xor(as_, m, 64);
        }
        if (lane < 4) {
            int j = node - 1;
            int b0 = lj * 4;
            out[(size_t)(b0 + 0) * n + j] = ax;
            out[(size_t)(b0 + 1) * n + j] = ay;
            out[(size_t)(b0 + 2) * n + j] = az;
            out[(size_t)(b0 + 3) * n + j] = as_;
        }
    }
}

// ---------------- fallback: direct device atomics ----------------
__global__ void edge_direct(const float* __restrict__ param,
                            const int* __restrict__ src,
                            const int* __restrict__ des,
                            const float* __restrict__ x,
                            float* __restrict__ out, int E, int n) {
    int e = blockIdx.x * blockDim.x + threadIdx.x;
    if (e >= E) return;
    float a = param[e], w = param[E + e], c = param[2 * E + e];
    int s = src[e], d = des[e];
#pragma unroll
    for (int b = 0; b < BATCH; ++b) {
        float vs = s ? x[(size_t)b * n + (s - 1)] : 0.0f;
        float vd = d ? x[(size_t)b * n + (d - 1)] : 0.0f;
        float st = a * tanhf(w * (vs - vd) + c);
        if (s) atomicAdd(out + (size_t)b * n + (s - 1), -st);
        if (d) atomicAdd(out + (size_t)b * n + (d - 1), st);
    }
}

extern "C" void kernel_launch(void* const* d_in, const int* in_sizes, int n_in,
                              void* d_out, int out_size, void* d_ws, size_t ws_size,
                              hipStream_t stream) {
    const float* x     = (const float*)d_in[1];
    const float* param = (const float*)d_in[2];
    const int*   src   = (const int*)d_in[3];
    const int*   des   = (const int*)d_in[4];
    float* out = (float*)d_out;

    int E = in_sizes[3];
    int n = in_sizes[1] / BATCH;   // N = 50000

    auto alignup = [](size_t v) { return (v + 255) & ~(size_t)255; };
    size_t auxBytes  = alignup((size_t)(n + 1) * BATCH * sizeof(float));
    size_t bhBytes   = alignup((size_t)SB * NPART * sizeof(unsigned));
    size_t psBytes   = alignup((size_t)(NPART + 1) * sizeof(unsigned));
    size_t btBytes   = alignup((size_t)NPART * sizeof(unsigned));
    size_t binBytes  = alignup((size_t)2 * E * sizeof(uint4));
    size_t need      = auxBytes + bhBytes + psBytes + btBytes + binBytes;

    size_t saLds = (size_t)LDSCAP * sizeof(uint4) + (2 * PS + 1 + 8) * sizeof(unsigned);

    if (ws_size >= need && (n + 1) <= NPART * PS && n <= 65534) {
        char* w = (char*)d_ws;
        float*    auxT      = (float*)w;     w += auxBytes;
        unsigned* blockHist = (unsigned*)w;  w += bhBytes;
        unsigned* partStart = (unsigned*)w;  w += psBytes;
        unsigned* binTotal  = (unsigned*)w;  w += btBytes;
        uint4*    bins      = (uint4*)w;

        hist1<<<SB, TPB, 0, stream>>>(src, des, x, auxT, blockHist, E, n);
        totals_k<<<NPART / 64, TPB, 0, stream>>>(blockHist, binTotal);
        scan_bins<<<1, TPB, 0, stream>>>(binTotal, partStart);
        offs_k<<<NPART / 64, TPB, 0, stream>>>(blockHist, partStart);
        scatter1<<<SB, TPB, 0, stream>>>(src, des, param, blockHist, bins, E);
        sort_accumulate<<<NPART, TPB, saLds, stream>>>(bins, partStart, auxT, out, n);
        return;
    }

    (void)hipMemsetAsync(out, 0, (size_t)out_size * sizeof(float), stream);
    edge_direct<<<(E + 255) / 256, 256, 0, stream>>>(param, src, des, x, out, E, n);
}

// Round 20
// 108.753 us; speedup vs baseline: 1.8610x; 1.0483x over previous
//
#include <hip/hip_runtime.h>

#define BATCH 16
#define PS 49                // nodes per partition
#define NPART 1024           // 1024*49 = 50176 >= 50001
#define SB 256               // hist/scatter blocks
#define TPB 1024
#define LDSCAP 3840          // records staged in LDS (mean 3125, +12.8 sigma); 61440 B

#define TWO_LOG2E 2.8853900817779268f   // 2*log2(e)

// Histogram of OWNER-endpoint partitions + fused aux build (LDS tile-transpose).
__global__ __launch_bounds__(TPB)
void hist1(const int* __restrict__ src, const int* __restrict__ des,
           const float* __restrict__ x, float* __restrict__ auxT,
           unsigned* __restrict__ blockHist, int E, int n) {
    __shared__ unsigned h[NPART];
    __shared__ float tile[64 * 17];
    int tid = threadIdx.x;
    for (int i = tid; i < NPART; i += TPB) h[i] = 0;
    if (blockIdx.x == 0 && tid < BATCH) auxT[tid] = 0.0f;   // node-0 zero row
    int nTiles = (n + 63) / 64;
    for (int t0 = blockIdx.x; t0 < nTiles; t0 += gridDim.x) {
        int i0 = t0 * 64;
        int b = tid >> 6, ii = tid & 63;
        float v = (i0 + ii < n) ? x[(size_t)b * n + i0 + ii] : 0.0f;
        __syncthreads();
        tile[ii * 17 + b] = v;
        __syncthreads();
        int i2 = i0 + (tid >> 4);
        if (i2 < n)
            auxT[(size_t)(i2 + 1) * BATCH + (tid & 15)] = tile[(tid >> 4) * 17 + (tid & 15)];
    }
    __syncthreads();
    long t = (long)blockIdx.x * TPB + tid;
    long stride = (long)gridDim.x * TPB * 4;
    for (long e0 = t * 4; e0 < E; e0 += stride) {
        int ne = (int)min((long)4, (long)E - e0);
        int ss[4], dd[4];
        if (ne == 4) {
            int4 sv = *(const int4*)(src + e0);
            int4 dv = *(const int4*)(des + e0);
            ss[0]=sv.x; ss[1]=sv.y; ss[2]=sv.z; ss[3]=sv.w;
            dd[0]=dv.x; dd[1]=dv.y; dd[2]=dv.z; dd[3]=dv.w;
        } else {
            for (int j = 0; j < ne; ++j) { ss[j] = src[e0+j]; dd[j] = des[e0+j]; }
        }
        for (int j = 0; j < ne; ++j) {
            atomicAdd(&h[ss[j] / PS], 1u);
            atomicAdd(&h[dd[j] / PS], 1u);
        }
    }
    __syncthreads();
    for (int i = tid; i < NPART; i += TPB)
        blockHist[(size_t)blockIdx.x * NPART + i] = h[i];
}

// Grid-parallel per-bin totals: 64 bins/block x 16 threads. Grid = NPART/64 = 16.
__global__ __launch_bounds__(TPB)
void totals_k(const unsigned* __restrict__ blockHist, unsigned* __restrict__ binTotal) {
    int tid = threadIdx.x;
    int bin = blockIdx.x * 64 + (tid >> 4);
    int j = tid & 15;
    unsigned s = 0;
    for (int r = j; r < SB; r += 16) s += blockHist[(size_t)r * NPART + bin];
#pragma unroll
    for (int m = 1; m < 16; m <<= 1) s += __shfl_xor(s, m, 64);
    if (j == 0) binTotal[bin] = s;
}

// One block: exclusive scan of 1024 bin totals -> partStart[0..1024].
__global__ __launch_bounds__(TPB)
void scan_bins(const unsigned* __restrict__ binTotal, unsigned* __restrict__ partStart) {
    __shared__ unsigned wsum[16];
    int tid = threadIdx.x;
    int lane = tid & 63, wv = tid >> 6;
    unsigned v = binTotal[tid];
    unsigned inc = v;
    for (int off = 1; off < 64; off <<= 1) {
        unsigned t = __shfl_up(inc, off, 64);
        if (lane >= off) inc += t;
    }
    if (lane == 63) wsum[wv] = inc;
    __syncthreads();
    if (tid < 16) {
        unsigned w = wsum[tid], winc = w;
        for (int off = 1; off < 16; off <<= 1) {
            unsigned t = __shfl_up(winc, off, 64);
            if (tid >= off) winc += t;
        }
        wsum[tid] = winc - w;
    }
    __syncthreads();
    unsigned excl = (inc - v) + wsum[wv];
    partStart[tid] = excl;
    if (tid == TPB - 1) partStart[NPART] = excl + v;
}

// Grid-parallel: blockHist -> per-(block,bin) scatter offsets. 64 bins/block x 16.
__global__ __launch_bounds__(TPB)
void offs_k(unsigned* __restrict__ blockHist, const unsigned* __restrict__ partStart) {
    int tid = threadIdx.x;
    int binLocal = tid >> 4;
    int bin = blockIdx.x * 64 + binLocal;
    int j = tid & 15;
    const int per = SB / 16;   // 16
    unsigned ls = 0;
    for (int r = j * per; r < (j + 1) * per; ++r)
        ls += blockHist[(size_t)r * NPART + bin];
    int waveBase = (binLocal & 3) * 16;
    unsigned excl = 0;
    for (int k = 0; k < 16; ++k) {
        unsigned v = __shfl(ls, waveBase + k, 64);
        if (k < j) excl += v;
    }
    unsigned run = partStart[bin] + excl;
    for (int r = j * per; r < (j + 1) * per; ++r) {
        unsigned tmp = blockHist[(size_t)r * NPART + bin];
        blockHist[(size_t)r * NPART + bin] = run;
        run += tmp;
    }
}

// Emit 2 owner-endpoint records per edge. TWO passes over the (L2-hot) edge
// chunk, bins [0,512) then [512,1024): halves the per-XCD partial-line write
// window below 4MB L2 -> full-line eviction, less write amplification.
__global__ __launch_bounds__(TPB)
void scatter1(const int* __restrict__ src, const int* __restrict__ des,
              const float* __restrict__ param, const unsigned* __restrict__ offsets,
              uint4* __restrict__ bins, int E) {
    __shared__ unsigned offs[NPART / 2];
    int tid = threadIdx.x;
    for (int half = 0; half < 2; ++half) {
        int binLo = half * (NPART / 2);
        __syncthreads();
        for (int i = tid; i < NPART / 2; i += TPB)
            offs[i] = offsets[(size_t)blockIdx.x * NPART + binLo + i];
        __syncthreads();
        long t = (long)blockIdx.x * TPB + tid;
        long stride = (long)gridDim.x * TPB * 4;
        for (long e0 = t * 4; e0 < E; e0 += stride) {
            int ne = (int)min((long)4, (long)E - e0);
            int ss[4], dd[4];
            float aa[4], ww[4], cc[4];
            if (ne == 4) {
                int4 sv = *(const int4*)(src + e0);
                int4 dv = *(const int4*)(des + e0);
                float4 av = *(const float4*)(param + e0);
                float4 wv = *(const float4*)(param + E + e0);
                float4 cv = *(const float4*)(param + 2 * (size_t)E + e0);
                ss[0]=sv.x; ss[1]=sv.y; ss[2]=sv.z; ss[3]=sv.w;
                dd[0]=dv.x; dd[1]=dv.y; dd[2]=dv.z; dd[3]=dv.w;
                aa[0]=av.x; aa[1]=av.y; aa[2]=av.z; aa[3]=av.w;
                ww[0]=wv.x; ww[1]=wv.y; ww[2]=wv.z; ww[3]=wv.w;
                cc[0]=cv.x; cc[1]=cv.y; cc[2]=cv.z; cc[3]=cv.w;
            } else {
                for (int j = 0; j < ne; ++j) {
                    ss[j] = src[e0+j]; dd[j] = des[e0+j];
                    aa[j] = param[e0+j]; ww[j] = param[E + e0 + j];
                    cc[j] = param[2 * (size_t)E + e0 + j];
                }
            }
            for (int j = 0; j < ne; ++j) {
                int s = ss[j], d = dd[j];
                float wq = ww[j] * TWO_LOG2E, cq = cc[j] * TWO_LOG2E;
                int ps = s / PS, pd = d / PS;
                if ((ps >> 9) == half) {
                    unsigned slot = atomicAdd(&offs[ps & 511], 1u);
                    bins[slot] = make_uint4((unsigned)s | ((unsigned)d << 16),
                                            __float_as_uint(-aa[j]), __float_as_uint(wq),
                                            __float_as_uint(cq));
                }
                if ((pd >> 9) == half) {
                    unsigned slot2 = atomicAdd(&offs[pd & 511], 1u);
                    bins[slot2] = make_uint4((unsigned)d | ((unsigned)s << 16),
                                             __float_as_uint(aa[j]), __float_as_uint(-wq),
                                             __float_as_uint(cq));
                }
            }
        }
    }
}

// st for one record given delta; a2 = 2*a hoisted.
static __device__ __forceinline__ float edge_eval(float a, float a2, float wq, float cq,
                                                  float dv) {
    float ez = __builtin_amdgcn_exp2f(__builtin_fmaf(wq, dv, cq));
    float r = __builtin_amdgcn_rcpf(ez + 1.0f);
    return __builtin_fmaf(-a2, r, a);   // a*(1-2r)
}

// Fused: rank-based counting sort into LDS (count atomics double as rank claims;
// pass 2 is atomic-free), then wave-per-node accumulate, direct out write.
__global__ __launch_bounds__(TPB)
void sort_accumulate(const uint4* __restrict__ bins, const unsigned* __restrict__ partStart,
                     const float* __restrict__ auxT, float* __restrict__ out, int n) {
    extern __shared__ uint4 srec[];                 // [LDSCAP]
    unsigned* bump = (unsigned*)(srec + LDSCAP);    // [PS] counts
    unsigned* ns   = bump + PS;                     // [PS+1] exclusive offsets
    int p = blockIdx.x;
    int tid = threadIdx.x;
    int lane = tid & 63;
    int wv = tid >> 6;
    unsigned lo = partStart[p], hi = partStart[p + 1];
    unsigned cl = min(hi - lo, (unsigned)LDSCAP);
    int base = p * PS;

    for (int i = tid; i < PS; i += TPB) bump[i] = 0;
    __syncthreads();
    // pass 1: count by owner; the returned value IS this record's rank in bin
    const unsigned* keys = (const unsigned*)bins;
    unsigned o0 = 0, o1 = 0, o2 = 0, o3 = 0;
    unsigned rk0 = 0, rk1 = 0, rk2 = 0, rk3 = 0;
    unsigned k0 = tid, k1 = tid + TPB, k2 = tid + 2 * TPB, k3 = tid + 3 * TPB;
    if (k0 < cl) { o0 = (keys[(size_t)(lo + k0) * 4] & 0xFFFFu) - (unsigned)base;
                   rk0 = atomicAdd(&bump[o0], 1u); }
    if (k1 < cl) { o1 = (keys[(size_t)(lo + k1) * 4] & 0xFFFFu) - (unsigned)base;
                   rk1 = atomicAdd(&bump[o1], 1u); }
    if (k2 < cl) { o2 = (keys[(size_t)(lo + k2) * 4] & 0xFFFFu) - (unsigned)base;
                   rk2 = atomicAdd(&bump[o2], 1u); }
    if (k3 < cl) { o3 = (keys[(size_t)(lo + k3) * 4] & 0xFFFFu) - (unsigned)base;
                   rk3 = atomicAdd(&bump[o3], 1u); }
    __syncthreads();
    // wave-parallel exclusive prefix over PS=49 bin counts (wave 0) -> ns
    if (wv == 0) {
        unsigned v = (lane < PS) ? bump[lane] : 0u;
        unsigned inc = v;
        for (int off = 1; off < 64; off <<= 1) {
            unsigned t = __shfl_up(inc, off, 64);
            if (lane >= off) inc += t;
        }
        if (lane < PS) ns[lane] = inc - v;
        if (lane == PS - 1) ns[PS] = inc;
    }
    __syncthreads();
    // pass 2: atomic-free placement (bin L2-hot from pass 1)
    if (k0 < cl) srec[ns[o0] + rk0] = bins[lo + k0];
    if (k1 < cl) srec[ns[o1] + rk1] = bins[lo + k1];
    if (k2 < cl) srec[ns[o2] + rk2] = bins[lo + k2];
    if (k3 < cl) srec[ns[o3] + rk3] = bins[lo + k3];
    __syncthreads();
    // pass 3: wave per node, 16 records in flight, lane-quad owns 4 batches
    int ri = lane >> 2, lj = lane & 3;
    const float4* aux4 = (const float4*)auxT;
    for (int nl = wv; nl < PS; nl += TPB / 64) {
        int node = base + nl;
        if (node == 0 || node > n) continue;
        unsigned l2 = ns[nl], h2 = ns[nl + 1];
        float4 vo = aux4[(size_t)node * 4 + lj];
        float ax = 0.0f, ay = 0.0f, az = 0.0f, as_ = 0.0f;
        for (unsigned kk = l2; kk < h2; kk += 16) {
            unsigned k = kk + (unsigned)ri;
            uint4 rec;
            if (k < h2) rec = srec[k];
            else { rec.x = 0u; rec.y = 0u; rec.z = 0u; rec.w = 0u; }
            unsigned rem = rec.x >> 16;
            float4 vr = aux4[(size_t)rem * 4 + lj];
            float a = __uint_as_float(rec.y);
            float a2 = a + a;
            float wq = __uint_as_float(rec.z);
            float cq = __uint_as_float(rec.w);
            ax  += edge_eval(a, a2, wq, cq, vo.x - vr.x);
            ay  += edge_eval(a, a2, wq, cq, vo.y - vr.y);
            az  += edge_eval(a, a2, wq, cq, vo.z - vr.z);
            as_ += edge_eval(a, a2, wq, cq, vo.w - vr.w);
        }
        // overflow tail (normally empty): filtered scan of un-staged records
        for (unsigned kk = lo + cl; kk < hi; kk += 16) {
            unsigned k = kk + (unsigned)ri;
            uint4 rec;
            if (k < hi) rec = bins[k];
            else { rec.x = 0u; rec.y = 0u; rec.z = 0u; rec.w = 0u; }
            if ((int)(rec.x & 0xFFFFu) != node) rec.y = 0u;   // a=0 -> no contribution
            unsigned rem = rec.x >> 16;
            float4 vr = aux4[(size_t)rem * 4 + lj];
            float a = __uint_as_float(rec.y);
            float a2 = a + a;
            float wq = __uint_as_float(rec.z);
            float cq = __uint_as_float(rec.w);
            ax  += edge_eval(a, a2, wq, cq, vo.x - vr.x);
            ay  += edge_eval(a, a2, wq, cq, vo.y - vr.y);
            az  += edge_eval(a, a2, wq, cq, vo.z - vr.z);
            as_ += edge_eval(a, a2, wq, cq, vo.w - vr.w);
        }
#pragma unroll
        for (int m = 4; m < 64; m <<= 1) {
            ax  += __shfl_xor(ax, m, 64);
            ay  += __shfl_xor(ay, m, 64);
            az  += __shfl_xor(az, m, 64);
            as_ += __shfl_xor(as_, m, 64);
        }
        if (lane < 4) {
            int j = node - 1;
            int b0 = lj * 4;
            out[(size_t)(b0 + 0) * n + j] = ax;
            out[(size_t)(b0 + 1) * n + j] = ay;
            out[(size_t)(b0 + 2) * n + j] = az;
            out[(size_t)(b0 + 3) * n + j] = as_;
        }
    }
}

// ---------------- fallback: direct device atomics ----------------
__global__ void edge_direct(const float* __restrict__ param,
                            const int* __restrict__ src,
                            const int* __restrict__ des,
                            const float* __restrict__ x,
                            float* __restrict__ out, int E, int n) {
    int e = blockIdx.x * blockDim.x + threadIdx.x;
    if (e >= E) return;
    float a = param[e], w = param[E + e], c = param[2 * E + e];
    int s = src[e], d = des[e];
#pragma unroll
    for (int b = 0; b < BATCH; ++b) {
        float vs = s ? x[(size_t)b * n + (s - 1)] : 0.0f;
        float vd = d ? x[(size_t)b * n + (d - 1)] : 0.0f;
        float st = a * tanhf(w * (vs - vd) + c);
        if (s) atomicAdd(out + (size_t)b * n + (s - 1), -st);
        if (d) atomicAdd(out + (size_t)b * n + (d - 1), st);
    }
}

extern "C" void kernel_launch(void* const* d_in, const int* in_sizes, int n_in,
                              void* d_out, int out_size, void* d_ws, size_t ws_size,
                              hipStream_t stream) {
    const float* x     = (const float*)d_in[1];
    const float* param = (const float*)d_in[2];
    const int*   src   = (const int*)d_in[3];
    const int*   des   = (const int*)d_in[4];
    float* out = (float*)d_out;

    int E = in_sizes[3];
    int n = in_sizes[1] / BATCH;   // N = 50000

    auto alignup = [](size_t v) { return (v + 255) & ~(size_t)255; };
    size_t auxBytes  = alignup((size_t)(n + 1) * BATCH * sizeof(float));
    size_t bhBytes   = alignup((size_t)SB * NPART * sizeof(unsigned));
    size_t psBytes   = alignup((size_t)(NPART + 1) * sizeof(unsigned));
    size_t btBytes   = alignup((size_t)NPART * sizeof(unsigned));
    size_t binBytes  = alignup((size_t)2 * E * sizeof(uint4));
    size_t need      = auxBytes + bhBytes + psBytes + btBytes + binBytes;

    size_t saLds = (size_t)LDSCAP * sizeof(uint4) + (2 * PS + 1 + 8) * sizeof(unsigned);

    if (ws_size >= need && (n + 1) <= NPART * PS && n <= 65534) {
        char* w = (char*)d_ws;
        float*    auxT      = (float*)w;     w += auxBytes;
        unsigned* blockHist = (unsigned*)w;  w += bhBytes;
        unsigned* partStart = (unsigned*)w;  w += psBytes;
        unsigned* binTotal  = (unsigned*)w;  w += btBytes;
        uint4*    bins      = (uint4*)w;

        hist1<<<SB, TPB, 0, stream>>>(src, des, x, auxT, blockHist, E, n);
        totals_k<<<NPART / 64, TPB, 0, stream>>>(blockHist, binTotal);
        scan_bins<<<1, TPB, 0, stream>>>(binTotal, partStart);
        offs_k<<<NPART / 64, TPB, 0, stream>>>(blockHist, partStart);
        scatter1<<<SB, TPB, 0, stream>>>(src, des, param, blockHist, bins, E);
        sort_accumulate<<<NPART, TPB, saLds, stream>>>(bins, partStart, auxT, out, n);
        return;
    }

    (void)hipMemsetAsync(out, 0, (size_t)out_size * sizeof(float), stream);
    edge_direct<<<(E + 255) / 256, 256, 0, stream>>>(param, src, des, x, out, E, n);
}